// Round 1
// 404.788 us; speedup vs baseline: 1.0086x; 1.0086x over previous
//
#include <hip/hip_runtime.h>
#include <hip/hip_bf16.h>

// Problem constants
constexpr int BB   = 16;
constexpr int TT_  = 392;          // T
constexpr int CC   = 512;          // C (= E)
constexpr int E8_  = 64;           // E/8
constexpr int KK   = 196;          // top_k
constexpr long TT2 = 153664;       // T*T
constexpr long OUT_HALF = 1229312; // B*T*K

// k_xt tiling
constexpr int NC2   = 98;          // K-chunks
constexpr int CH2   = 1568;        // K per chunk (NC2*CH2 = T*T)
constexpr int BK2   = 224;         // K per LDS stage
constexpr int NSTEP = 7;           // CH2/BK2
constexpr int NJT   = 13;          // j-tiles of 32 (13*32=416 >= 392)
// LDS row strides in bf16 elems. Chosen so byte-stride ≡ 8 (mod 16):
// dword-stride ≡ 2 (mod 4) -> 16 n-lanes hit 16 distinct banks (2-way = free).
constexpr int LDW = 228;           // k_xt rows (224 elems + pad)
constexpr int LDX = 36;            // k_xi rows (32 elems + pad)
constexpr int LDA = 68;            // k_att rows (64 elems + pad)

typedef __bf16 bf16_t;
typedef bf16_t bf16x8 __attribute__((ext_vector_type(8)));
typedef float  f32x4  __attribute__((ext_vector_type(4)));

static __device__ __forceinline__ unsigned int pk2(float a, float b) {
    unsigned short lo = __builtin_bit_cast(unsigned short, (bf16_t)a);
    unsigned short hi = __builtin_bit_cast(unsigned short, (bf16_t)b);
    return ((unsigned int)hi << 16) | (unsigned int)lo;
}
// 8B-aligned fragment load: two ds_read_b64 (rows are 8-mod-16 aligned by design)
static __device__ __forceinline__ bf16x8 ld_frag(const bf16_t* p) {
    uint2 lo = *(const uint2*)p;
    uint2 hi = *(const uint2*)(p + 4);
    uint4 u = make_uint4(lo.x, lo.y, hi.x, hi.y);
    return __builtin_bit_cast(bf16x8, u);
}

// ---------------------------------------------------------------- xi = bf16(x @ W_dim^T + b_dim)  (MFMA)
// grid 98, block 256 (4 waves). Block tile: 64 m-rows x 64 e. K=512 in 16 steps of 32.
// Pipelined: stage kt+1 loads issued into regs before kt's MFMAs; LDS ping-pong, 1 barrier/stage.
// Also zero-inits xt (ws is poisoned 0xAA every call).
__global__ __launch_bounds__(256) void k_xi(const float* __restrict__ x,
                                            const float* __restrict__ Wd,
                                            const float* __restrict__ bd,
                                            unsigned short* __restrict__ xi_b,
                                            float* __restrict__ xt) {
    __shared__ bf16_t Xl[2][64 * LDX];
    __shared__ bf16_t Wl[2][64 * LDX];
    int tid = threadIdx.x;
    if (blockIdx.x < 25) {
        int o = blockIdx.x * 256 + tid;
        if (o < BB * TT_) xt[o] = 0.f;
    }
    int m0 = blockIdx.x * 64;
    int wv = tid >> 6, lane = tid & 63;
    int n = lane & 15, quad = lane >> 4;

    // staging coords: s = t*256+tid -> r = t*32 + (tid>>3), c4 = tid&7
    int rr = tid >> 3, c4 = tid & 7;
    const float* xsrc = x  + (size_t)(m0 + rr) * CC + c4 * 4;
    const float* wsrc = Wd + (size_t)rr * CC + c4 * 4;
    int dst = rr * LDX + c4 * 4;

    f32x4 xv[2], wq[2];
    auto LOADS = [&](int kt) {
        #pragma unroll
        for (int t = 0; t < 2; ++t) {
            xv[t] = *(const f32x4*)(xsrc + (size_t)t * 32 * CC + kt * 32);
            wq[t] = *(const f32x4*)(wsrc + (size_t)t * 32 * CC + kt * 32);
        }
    };
    auto WRITE = [&](int p) {
        #pragma unroll
        for (int t = 0; t < 2; ++t) {
            *(uint2*)(&Xl[p][dst + t * 32 * LDX]) =
                make_uint2(pk2(xv[t].x, xv[t].y), pk2(xv[t].z, xv[t].w));
            *(uint2*)(&Wl[p][dst + t * 32 * LDX]) =
                make_uint2(pk2(wq[t].x, wq[t].y), pk2(wq[t].z, wq[t].w));
        }
    };

    f32x4 acc[4] = {};
    LOADS(0); WRITE(0); __syncthreads();
    int p = 0;
    for (int kt = 0; kt < 16; ++kt) {
        if (kt + 1 < 16) LOADS(kt + 1);
        bf16x8 a = ld_frag(&Xl[p][(wv * 16 + n) * LDX + quad * 8]);
        #pragma unroll
        for (int nt = 0; nt < 4; ++nt) {
            bf16x8 b = ld_frag(&Wl[p][(nt * 16 + n) * LDX + quad * 8]);
            acc[nt] = __builtin_amdgcn_mfma_f32_16x16x32_bf16(a, b, acc[nt], 0, 0, 0);
        }
        if (kt + 1 < 16) WRITE(p ^ 1);
        __syncthreads();
        p ^= 1;
    }
    #pragma unroll
    for (int nt = 0; nt < 4; ++nt)
        #pragma unroll
        for (int r = 0; r < 4; ++r) {
            int m = m0 + wv * 16 + quad * 4 + r;
            int e = nt * 16 + n;
            xi_b[(size_t)m * E8_ + e] =
                __builtin_bit_cast(unsigned short, (bf16_t)(acc[nt][r] + bd[e]));
        }
}

// ---------------------------------------------------------------- fused scores + softmax -> att bf16
// grid (16 b, 7 ti-tiles), block 256 (4 waves). Wave: 16 ti x full 392 tj (25 n-tiles).
// xi is already bf16 -> staging is a pure copy (half the traffic, no cvt VALU).
__global__ __launch_bounds__(256) void k_att(const unsigned short* __restrict__ xi_b,
                                             unsigned short* __restrict__ att_b) {
    __shared__ bf16_t Xb[400 * LDA];
    int b = blockIdx.x, tb = blockIdx.y;
    int tid = threadIdx.x;
    int wv = tid >> 6, lane = tid & 63;
    int n = lane & 15, quad = lane >> 4;
    // stage xi batch (392x64 bf16), rows 392..399 zero. 400*8 = 3200 uint4-of-8-elems slots.
    #pragma unroll
    for (int t = 0; t < 13; ++t) {
        int s = t * 256 + tid;              // 0..3327, guard 3200
        if (s < 3200) {
            int r = s >> 3, c8 = s & 7;
            uint2 lo = make_uint2(0u, 0u), hi = make_uint2(0u, 0u);
            if (r < TT_) {
                uint4 v = *(const uint4*)(xi_b + ((size_t)(b * TT_ + r)) * E8_ + c8 * 8);
                lo = make_uint2(v.x, v.y);
                hi = make_uint2(v.z, v.w);
            }
            *(uint2*)(&Xb[r * LDA + c8 * 8])     = lo;
            *(uint2*)(&Xb[r * LDA + c8 * 8 + 4]) = hi;
        }
    }
    __syncthreads();
    int arow = tb * 64 + wv * 16 + n;
    if (arow > 399) arow = 399;
    bf16x8 a0 = ld_frag(&Xb[arow * LDA + quad * 8]);        // k 0..31
    bf16x8 a1 = ld_frag(&Xb[arow * LDA + 32 + quad * 8]);   // k 32..63
    f32x4 acc[25];
    #pragma unroll
    for (int nt = 0; nt < 25; ++nt) acc[nt] = (f32x4){0.f, 0.f, 0.f, 0.f};
    #pragma unroll
    for (int nt = 0; nt < 25; ++nt) {
        bf16x8 b0 = ld_frag(&Xb[(nt * 16 + n) * LDA + quad * 8]);
        bf16x8 b1 = ld_frag(&Xb[(nt * 16 + n) * LDA + 32 + quad * 8]);
        acc[nt] = __builtin_amdgcn_mfma_f32_16x16x32_bf16(a0, b0, acc[nt], 0, 0, 0);
        acc[nt] = __builtin_amdgcn_mfma_f32_16x16x32_bf16(a1, b1, acc[nt], 0, 0, 0);
    }
    // per-lane rows ti = quad*4 + r (within wave tile); cols tj = nt*16 + n.
    const float scaler = 1.0f / 512.0f;
    float mx[4] = {-1e30f, -1e30f, -1e30f, -1e30f};
    #pragma unroll
    for (int nt = 0; nt < 25; ++nt) {
        bool valid = (nt * 16 + n) < TT_;
        #pragma unroll
        for (int r = 0; r < 4; ++r) {
            float v = valid ? acc[nt][r] * scaler : -1e30f;
            acc[nt][r] = v;
            mx[r] = fmaxf(mx[r], v);
        }
    }
    #pragma unroll
    for (int r = 0; r < 4; ++r) {
        #pragma unroll
        for (int o = 1; o < 16; o <<= 1) mx[r] = fmaxf(mx[r], __shfl_xor(mx[r], o, 64));
    }
    float sm[4] = {0.f, 0.f, 0.f, 0.f};
    #pragma unroll
    for (int nt = 0; nt < 25; ++nt)
        #pragma unroll
        for (int r = 0; r < 4; ++r) {
            float e = __expf(acc[nt][r] - mx[r]);
            acc[nt][r] = e;
            sm[r] += e;
        }
    #pragma unroll
    for (int r = 0; r < 4; ++r) {
        #pragma unroll
        for (int o = 1; o < 16; o <<= 1) sm[r] += __shfl_xor(sm[r], o, 64);
        sm[r] = 1.0f / sm[r];
    }
    unsigned short* dst = att_b + (size_t)b * TT2;
    #pragma unroll
    for (int r = 0; r < 4; ++r) {
        int ti = tb * 64 + wv * 16 + quad * 4 + r;
        if (ti < TT_) {
            #pragma unroll
            for (int nt = 0; nt < 25; ++nt) {
                int tj = nt * 16 + n;
                if (tj < TT_)
                    dst[(size_t)ti * TT_ + tj] =
                        __builtin_bit_cast(unsigned short, (bf16_t)(acc[nt][r] * sm[r]));
            }
        }
    }
}

// ---------------------------------------------------------------- xt via MFMA + fp32 atomic accumulate
// grid (98 chunks, 13 j-tiles), block 128 (2 waves). Tile: 16 b x 32 j, K = 1568 in 7 stages of 224.
// Pipelined: stage s+1 global loads issued into regs BEFORE stage s MFMAs; LDS ping-pong,
// one barrier per stage -> loads stay in flight across compute (T14 issue-early/write-late).
__global__ __launch_bounds__(128) void k_xt(const float* __restrict__ Wt,
                                            const unsigned short* __restrict__ att_b,
                                            float* __restrict__ xt) {
    __shared__ bf16_t Wl[2][32 * LDW];     // 2 x 14592 B
    __shared__ bf16_t Al[2][16 * LDW];     // 2 x  7296 B   (total 43776 B -> 3 blocks/CU)
    int c = blockIdx.x, jt = blockIdx.y;
    int tid = threadIdx.x;
    int wv = tid >> 6, lane = tid & 63;
    int n = lane & 15, quad = lane >> 4;
    long kbase = (long)c * CH2;

    // W staging coords (14 f32x4 per thread per stage; 896B contiguous per row-chunk)
    const float* wsrc[14];
    int wdst[14];
    #pragma unroll
    for (int t = 0; t < 14; ++t) {
        int idx = t * 128 + tid;            // 0..1791
        int r = idx / 56, col = idx - r * 56;
        int jg = jt * 32 + r; if (jg > 391) jg = 391;
        wsrc[t] = Wt + (size_t)jg * TT2 + kbase + col * 4;
        wdst[t] = r * LDW + col * 4;
    }
    // att staging coords (already bf16; 16 rows x 28 x 16B per stage)
    const unsigned short* asrc[4];
    int adst[4];
    bool aok[4];
    #pragma unroll
    for (int t = 0; t < 4; ++t) {
        int idx = t * 128 + tid;            // 0..511, guard 448
        aok[t] = idx < 448;
        int r = aok[t] ? idx / 28 : 0;
        int q = aok[t] ? idx - r * 28 : 0;
        asrc[t] = att_b + (size_t)r * TT2 + kbase + q * 8;
        adst[t] = r * LDW + q * 8;
    }

    f32x4 wb[14];
    uint4 ab[4];
    auto LOADS = [&](int s) {
        long k0 = (long)s * BK2;
        #pragma unroll
        for (int t = 0; t < 14; ++t) wb[t] = *(const f32x4*)(wsrc[t] + k0);
        #pragma unroll
        for (int t = 0; t < 4; ++t) if (aok[t]) ab[t] = *(const uint4*)(asrc[t] + k0);
    };
    auto WRITE = [&](int p) {
        #pragma unroll
        for (int t = 0; t < 14; ++t)
            *(uint2*)(&Wl[p][wdst[t]]) =
                make_uint2(pk2(wb[t].x, wb[t].y), pk2(wb[t].z, wb[t].w));
        #pragma unroll
        for (int t = 0; t < 4; ++t) if (aok[t]) {
            *(uint2*)(&Al[p][adst[t]])     = make_uint2(ab[t].x, ab[t].y);
            *(uint2*)(&Al[p][adst[t] + 4]) = make_uint2(ab[t].z, ab[t].w);
        }
    };

    f32x4 acc = {0.f, 0.f, 0.f, 0.f};
    LOADS(0); WRITE(0); __syncthreads();
    int p = 0;
    for (int s = 0; s < NSTEP; ++s) {
        if (s + 1 < NSTEP) LOADS(s + 1);    // issue next-stage HBM loads into regs
        #pragma unroll
        for (int m = 0; m < 7; ++m) {       // compute current stage from buf p
            int k = m * 32;
            bf16x8 a = ld_frag(&Al[p][n * LDW + k + quad * 8]);
            bf16x8 b = ld_frag(&Wl[p][(wv * 16 + n) * LDW + k + quad * 8]);
            acc = __builtin_amdgcn_mfma_f32_16x16x32_bf16(a, b, acc, 0, 0, 0);
        }
        if (s + 1 < NSTEP) WRITE(p ^ 1);    // vmcnt wait lands here, after compute
        __syncthreads();
        p ^= 1;
    }
    int j = jt * 32 + wv * 16 + n;
    if (j < TT_) {
        #pragma unroll
        for (int r = 0; r < 4; ++r)
            unsafeAtomicAdd(&xt[(size_t)(quad * 4 + r) * TT_ + j], acc[r]);
    }
}

// ---------------------------------------------------------------- offsets -> unnormalized sample coord ix
// Folds b_time into the dot (xt holds the bias-free sums).
__global__ __launch_bounds__(256) void k_off(const float* __restrict__ xt,
                                             const float* __restrict__ bt,
                                             const float* __restrict__ Wa,
                                             const float* __restrict__ Wd,
                                             float* __restrict__ wix) {
    int o = blockIdx.x * 256 + threadIdx.x;
    if (o >= 2 * BB * KK) return;                  // 6272
    int which = o / (BB * KK);                     // 0 = a, 1 = d
    int rem = o - which * (BB * KK);
    int b = rem / KK;
    int k = rem - b * KK;
    const f32x4* __restrict__ wr = (const f32x4*)((which ? Wd : Wa) + (size_t)k * TT_);
    const f32x4* __restrict__ xr = (const f32x4*)(xt + (size_t)b * TT_);
    const f32x4* __restrict__ br = (const f32x4*)bt;
    float acc = 0.f;
    #pragma unroll 2
    for (int q = 0; q < TT_ / 4; ++q) {
        f32x4 w = wr[q], x = xr[q], bb = br[q];
        acc += (x.x + bb.x) * w.x + (x.y + bb.y) * w.y
             + (x.z + bb.z) * w.z + (x.w + bb.w) * w.w;
    }
    float off = tanhf(acc) * 2.0f;                 // * RECEPTIVE_FIELD
    float idx = (float)(2 * k + which) + off;      // arange(0,t,2) or arange(1,t+1,2)
    float g = 2.0f * idx / 391.0f - 1.0f;          // normalize_grid, denom = t-1
    float ix = ((g + 1.0f) * 512.0f - 1.0f) * 0.5f; // grid_sample unnormalize, c=512
    wix[o] = ix;
}

// ---------------------------------------------------------------- bilinear gather along channels
__global__ __launch_bounds__(256) void k_sample(const float* __restrict__ x,
                                                const float* __restrict__ wix,
                                                float* __restrict__ out) {
    __shared__ float xr[4][512];
    int b = blockIdx.x, t0 = blockIdx.y * 4;
    int tid = threadIdx.x;
    const float* src = x + ((size_t)b * TT_ + t0) * CC;
    #pragma unroll
    for (int s = 0; s < 2; ++s) {
        int idx = s * 256 + tid;                   // 0..511 float4 slots
        ((f32x4*)xr)[idx] = ((const f32x4*)src)[idx];
    }
    __syncthreads();
    for (int w = tid; w < 2 * 4 * KK; w += 256) {  // 1568 items
        int which = (w >= 4 * KK) ? 1 : 0;
        int rem = w - which * 4 * KK;
        int tl = rem / KK;
        int k = rem - tl * KK;
        float ix = wix[(size_t)which * (BB * KK) + b * KK + k];
        float x0f = floorf(ix);
        float w1 = ix - x0f;
        int c0 = (int)x0f;
        int c1 = c0 + 1;
        c0 = min(max(c0, 0), CC - 1);
        c1 = min(max(c1, 0), CC - 1);
        float v0 = xr[tl][c0], v1 = xr[tl][c1];
        out[(size_t)which * OUT_HALF + ((size_t)(b * TT_) + t0 + tl) * KK + k] =
            v0 * (1.0f - w1) + v1 * w1;
    }
}

extern "C" void kernel_launch(void* const* d_in, const int* in_sizes, int n_in,
                              void* d_out, int out_size, void* d_ws, size_t ws_size,
                              hipStream_t stream) {
    const float* x_in   = (const float*)d_in[0];
    const float* W_dim  = (const float*)d_in[1];
    const float* b_dim  = (const float*)d_in[2];
    const float* W_time = (const float*)d_in[3];
    const float* b_time = (const float*)d_in[4];
    const float* W_offa = (const float*)d_in[5];
    const float* W_offd = (const float*)d_in[6];
    float* out = (float*)d_out;
    float* ws  = (float*)d_ws;

    // ws layout (float units):
    unsigned short* att_b = (unsigned short*)ws;            // 16*153664 bf16 = 1,229,312 fl
    unsigned short* xi_b  = (unsigned short*)(ws + 1229312); // 6272*64 bf16 (region kept fl-sized)
    float*          xt    = ws + 1630720;                    //     6,272 fl (zeroed by k_xi)
    float*          wix   = ws + 1636992;                    //     6,272 fl
    // total ~6.6 MB

    k_xi<<<98, 256, 0, stream>>>(x_in, W_dim, b_dim, xi_b, xt);
    k_att<<<dim3(BB, 7), 256, 0, stream>>>(xi_b, att_b);
    k_xt<<<dim3(NC2, NJT), 128, 0, stream>>>(W_time, att_b, xt);
    k_off<<<25, 256, 0, stream>>>(xt, b_time, W_offa, W_offd, wix);
    k_sample<<<dim3(BB, TT_ / 4), 256, 0, stream>>>(x_in, wix, out);
}